// Round 7
// baseline (78.411 us; speedup 1.0000x reference)
//
#include <hip/hip_runtime.h>
#include <math.h>

#define N_HALF 4096
#define D 64
#define M_TOT 8192
#define NPAIR 2080      // 64*65/2 upper-triangle 128x128 tile pairs
#define MAIN_GRID 1024  // 4 blocks/CU resident; ~2 pairs per block

typedef short short8_t __attribute__((ext_vector_type(8)));
typedef unsigned short us8 __attribute__((ext_vector_type(8)));
typedef float f32x4 __attribute__((ext_vector_type(4)));

// Device-global scratch (fully rewritten by plain stores every call).
__device__ unsigned short Fhi[M_TOT * D];  // 1 MB fragment-major bf16 hi
__device__ unsigned short Flo[M_TOT * D];  // 1 MB bf16 lo residue
__device__ float g_norms[M_TOT];
__device__ float g_pssq[256];      // per-prep-block sum-of-squares partials
__device__ float g_pcol[256 * D];  // per-prep-block column-sum partials [b][c]
__device__ float g_coef;           // base exp2 coefficient g0
__device__ double g_part[NPAIR];   // per-pair signed partial sums
__device__ float g_dummy[NPAIR];   // ablation sink (write-only)

static __device__ inline unsigned short f2bf(float x) {
    union { float f; unsigned u; } v; v.f = x;
    unsigned r = v.u + 0x7fff + ((v.u >> 16) & 1);  // RNE
    return (unsigned short)(r >> 16);
}
static __device__ inline float bf2f(unsigned short h) {
    union { unsigned u; float f; } v; v.u = ((unsigned)h) << 16;
    return v.f;
}
static __device__ inline void keep8(short8_t v) {  // anti-DCE (rule #17)
    f32x4 f = __builtin_bit_cast(f32x4, v);
    asm volatile("" :: "v"(f[0]), "v"(f[1]), "v"(f[2]), "v"(f[3]));
}

// Fused: split-bf16 convert to fragment-major + row norms + block partials.
// F[rt][s][lane][e] = X[rt*16 + (lane&15)][s*32 + (lane>>4)*8 + e]
__global__ __launch_bounds__(256) void mmd_prep(const float* __restrict__ src,
                                                const float* __restrict__ tgt) {
    __shared__ float cs[D];
    __shared__ float hn[4][16];
    int t = threadIdx.x;
    if (t < D) cs[t] = 0.f;
    __syncthreads();
    int tid = blockIdx.x * 256 + t;  // 65536 threads total
    int l = tid & 63;
    int rs = tid >> 6;
    int s = rs & 1, rt = rs >> 1;
    int row = rt * 16 + (l & 15);
    int k0 = s * 32 + (l >> 4) * 8;
    const float* X = (row < N_HALF) ? src + (size_t)row * D
                                    : tgt + (size_t)(row - N_HALF) * D;
    float4 v0 = ((const float4*)(X + k0))[0];
    float4 v1 = ((const float4*)(X + k0))[1];
    float vs[8] = {v0.x, v0.y, v0.z, v0.w, v1.x, v1.y, v1.z, v1.w};
    us8 h, o;
    float p = 0.f;
#pragma unroll
    for (int e = 0; e < 8; ++e) {
        unsigned short hi = f2bf(vs[e]);
        h[e] = hi;
        o[e] = f2bf(vs[e] - bf2f(hi));
        p += vs[e] * vs[e];
    }
    ((us8*)Fhi)[tid] = h;
    ((us8*)Flo)[tid] = o;
#pragma unroll
    for (int e = 0; e < 8; ++e) atomicAdd(&cs[k0 + e], vs[e]);  // LDS only
    p += __shfl_down(p, 32, 64);
    p += __shfl_down(p, 16, 64);
    int w = t >> 6;
    if (l < 16) hn[w][l] = p;
    __syncthreads();
    if (t < 64) {
        float nr = 0.f;
        int tile = t >> 4, r = t & 15;
        if (t < 32) {
            nr = hn[tile * 2][r] + hn[tile * 2 + 1][r];
            g_norms[(blockIdx.x * 2 + tile) * 16 + r] = nr;
        }
        nr += __shfl_down(nr, 32, 64);
        nr += __shfl_down(nr, 16, 64);
        nr += __shfl_down(nr, 8, 64);
        nr += __shfl_down(nr, 4, 64);
        nr += __shfl_down(nr, 2, 64);
        nr += __shfl_down(nr, 1, 64);
        if (t == 0) g_pssq[blockIdx.x] = nr;
    }
    if (t < D) g_pcol[blockIdx.x * D + t] = cs[t];
}

// Bandwidth coefficient, one small block (hoisted out of main).
__global__ __launch_bounds__(256) void mmd_bw() {
    __shared__ float scol[4][64];
    __shared__ float sssq[4];
    int t = threadIdx.x, w = t >> 6, l = t & 63;
    float csum = 0.f;
#pragma unroll 16
    for (int q = 0; q < 64; ++q) csum += g_pcol[(w * 64 + q) * 64 + l];
    float sq = g_pssq[w * 64 + l];
#pragma unroll
    for (int off = 32; off; off >>= 1) sq += __shfl_xor(sq, off, 64);
    scol[w][l] = csum;
    if (l == 0) sssq[w] = sq;
    __syncthreads();
    if (t < 64) {
        float colsum = (scol[0][l] + scol[1][l]) + (scol[2][l] + scol[3][l]);
        float s2 = colsum * colsum;
#pragma unroll
        for (int off = 32; off; off >>= 1) s2 += __shfl_xor(s2, off, 64);
        if (t == 0) {
            float ssq = (sssq[0] + sssq[1]) + (sssq[2] + sssq[3]);
            const float M = (float)M_TOT;
            float sumL2 = 2.f * M * ssq - 2.f * s2;
            float bwq = sumL2 / (M * M - M) * 0.25f;
            g_coef = -1.4426950408889634f / (bwq * 16.f);
        }
    }
}

static __device__ inline void decode_pair(int id, int& bi, int& bj) {
    bi = (int)(64.5f - sqrtf(4160.25f - 2.0f * (float)id));
    while ((64 * (bi + 1) - ((bi + 1) * bi) / 2) <= id) ++bi;
    while ((64 * bi - (bi * (bi - 1)) / 2) > id) --bi;
    bj = bi + (id - (64 * bi - (bi * (bi - 1)) / 2));
}

// Producer: identical math to R6, minus the per-block bandwidth preamble.
__global__ __launch_bounds__(256, 2) void mmd_main() {
    __shared__ float sred[4];
    int t = threadIdx.x, w = t >> 6, l = t & 63;
    int wr = w >> 1, wc = w & 1;
    float g0 = g_coef;
    float c2 = -2.f * g0;
    const short8_t* FH = (const short8_t*)Fhi;
    const short8_t* FL = (const short8_t*)Flo;

    for (int id = blockIdx.x; id < NPAIR; id += MAIN_GRID) {
        int bi, bj; decode_pair(id, bi, bj);

        short8_t ah[2][4], al[2][4], bh[2][4];
#pragma unroll
        for (int s = 0; s < 2; ++s)
#pragma unroll
            for (int n = 0; n < 4; ++n)
                bh[s][n] = FH[((bj * 8 + wc * 4 + n) * 2 + s) * 64 + l];
#pragma unroll
        for (int s = 0; s < 2; ++s)
#pragma unroll
            for (int m = 0; m < 4; ++m) {
                int fi = ((bi * 8 + wr * 4 + m) * 2 + s) * 64 + l;
                ah[s][m] = FH[fi];
                al[s][m] = FL[fi];
            }

        f32x4 acc[4][4] = {};
#pragma unroll
        for (int s = 0; s < 2; ++s)
#pragma unroll
            for (int m = 0; m < 4; ++m)
#pragma unroll
                for (int n = 0; n < 4; ++n) {
                    acc[m][n] = __builtin_amdgcn_mfma_f32_16x16x32_bf16(al[s][m], bh[s][n], acc[m][n], 0, 0, 0);
                    acc[m][n] = __builtin_amdgcn_mfma_f32_16x16x32_bf16(ah[s][m], bh[s][n], acc[m][n], 0, 0, 0);
                }

        float nas[4][4];
#pragma unroll
        for (int m = 0; m < 4; ++m) {
            float4 v = *(const float4*)&g_norms[bi * 128 + wr * 64 + m * 16 + (l >> 4) * 4];
            nas[m][0] = v.x * g0; nas[m][1] = v.y * g0;
            nas[m][2] = v.z * g0; nas[m][3] = v.w * g0;
        }
        float nbv[4];
#pragma unroll
        for (int n = 0; n < 4; ++n)
            nbv[n] = g_norms[bj * 128 + wc * 64 + n * 16 + (l & 15)] * g0;

        float part4[4] = {0.f, 0.f, 0.f, 0.f};
#pragma unroll
        for (int m = 0; m < 4; ++m)
#pragma unroll
            for (int n = 0; n < 4; ++n)
#pragma unroll
                for (int r = 0; r < 4; ++r) {
                    float t0 = fmaf(acc[m][n][r], c2, nas[m][r] + nbv[n]);
                    float k4 = __builtin_amdgcn_exp2f(t0);
                    float k3 = k4 * k4;
                    float k2 = k3 * k3;
                    float k1 = k2 * k2;
                    float k0 = k1 * k1;
                    part4[r] += (k4 + k3) + ((k2 + k1) + k0);
                }
        float part = (part4[0] + part4[1]) + (part4[2] + part4[3]);

#pragma unroll
        for (int off = 32; off; off >>= 1) part += __shfl_down(part, off, 64);
        if (l == 0) sred[w] = part;
        __syncthreads();
        if (t == 0) {
            float tot = (sred[0] + sred[1]) + (sred[2] + sred[3]);
            float sgn = ((bi < 32) == (bj < 32)) ? 1.f : -1.f;
            float scl = (bi == bj) ? 1.f : 2.f;
            g_part[id] = (double)tot * (double)(sgn * scl);
        }
        __syncthreads();
    }
}

// ---- Ablation 1: decode + fragment loads only (keepalive'd). ----
__global__ __launch_bounds__(256, 2) void mmd_abl_loads() {
    int t = threadIdx.x, w = t >> 6, l = t & 63;
    int wr = w >> 1, wc = w & 1;
    const short8_t* FH = (const short8_t*)Fhi;
    const short8_t* FL = (const short8_t*)Flo;
    for (int id = blockIdx.x; id < NPAIR; id += MAIN_GRID) {
        int bi, bj; decode_pair(id, bi, bj);
#pragma unroll
        for (int s = 0; s < 2; ++s)
#pragma unroll
            for (int n = 0; n < 4; ++n)
                keep8(FH[((bj * 8 + wc * 4 + n) * 2 + s) * 64 + l]);
#pragma unroll
        for (int s = 0; s < 2; ++s)
#pragma unroll
            for (int m = 0; m < 4; ++m) {
                int fi = ((bi * 8 + wr * 4 + m) * 2 + s) * 64 + l;
                keep8(FH[fi]);
                keep8(FL[fi]);
            }
        if (t == 0) g_dummy[id] = (float)bi;
    }
}

// ---- Ablation 2: loads + MFMAs (acc consumed by cheap sum). ----
__global__ __launch_bounds__(256, 2) void mmd_abl_loadmfma() {
    __shared__ float sred[4];
    int t = threadIdx.x, w = t >> 6, l = t & 63;
    int wr = w >> 1, wc = w & 1;
    const short8_t* FH = (const short8_t*)Fhi;
    const short8_t* FL = (const short8_t*)Flo;
    for (int id = blockIdx.x; id < NPAIR; id += MAIN_GRID) {
        int bi, bj; decode_pair(id, bi, bj);
        short8_t ah[2][4], al[2][4], bh[2][4];
#pragma unroll
        for (int s = 0; s < 2; ++s)
#pragma unroll
            for (int n = 0; n < 4; ++n)
                bh[s][n] = FH[((bj * 8 + wc * 4 + n) * 2 + s) * 64 + l];
#pragma unroll
        for (int s = 0; s < 2; ++s)
#pragma unroll
            for (int m = 0; m < 4; ++m) {
                int fi = ((bi * 8 + wr * 4 + m) * 2 + s) * 64 + l;
                ah[s][m] = FH[fi];
                al[s][m] = FL[fi];
            }
        f32x4 acc[4][4] = {};
#pragma unroll
        for (int s = 0; s < 2; ++s)
#pragma unroll
            for (int m = 0; m < 4; ++m)
#pragma unroll
                for (int n = 0; n < 4; ++n) {
                    acc[m][n] = __builtin_amdgcn_mfma_f32_16x16x32_bf16(al[s][m], bh[s][n], acc[m][n], 0, 0, 0);
                    acc[m][n] = __builtin_amdgcn_mfma_f32_16x16x32_bf16(ah[s][m], bh[s][n], acc[m][n], 0, 0, 0);
                }
        float part = 0.f;
#pragma unroll
        for (int m = 0; m < 4; ++m)
#pragma unroll
            for (int n = 0; n < 4; ++n)
#pragma unroll
                for (int r = 0; r < 4; ++r) part += acc[m][n][r];
#pragma unroll
        for (int off = 32; off; off >>= 1) part += __shfl_down(part, off, 64);
        if (l == 0) sred[w] = part;
        __syncthreads();
        if (t == 0) g_dummy[id] = sred[0] + sred[1] + sred[2] + sred[3];
        __syncthreads();
    }
}

// ---- Ablation 3: full pipeline minus the exp2 chain (sums t0 instead). ----
__global__ __launch_bounds__(256, 2) void mmd_abl_noexp() {
    __shared__ float sred[4];
    int t = threadIdx.x, w = t >> 6, l = t & 63;
    int wr = w >> 1, wc = w & 1;
    float g0 = g_coef;
    float c2 = -2.f * g0;
    const short8_t* FH = (const short8_t*)Fhi;
    const short8_t* FL = (const short8_t*)Flo;
    for (int id = blockIdx.x; id < NPAIR; id += MAIN_GRID) {
        int bi, bj; decode_pair(id, bi, bj);
        short8_t ah[2][4], al[2][4], bh[2][4];
#pragma unroll
        for (int s = 0; s < 2; ++s)
#pragma unroll
            for (int n = 0; n < 4; ++n)
                bh[s][n] = FH[((bj * 8 + wc * 4 + n) * 2 + s) * 64 + l];
#pragma unroll
        for (int s = 0; s < 2; ++s)
#pragma unroll
            for (int m = 0; m < 4; ++m) {
                int fi = ((bi * 8 + wr * 4 + m) * 2 + s) * 64 + l;
                ah[s][m] = FH[fi];
                al[s][m] = FL[fi];
            }
        f32x4 acc[4][4] = {};
#pragma unroll
        for (int s = 0; s < 2; ++s)
#pragma unroll
            for (int m = 0; m < 4; ++m)
#pragma unroll
                for (int n = 0; n < 4; ++n) {
                    acc[m][n] = __builtin_amdgcn_mfma_f32_16x16x32_bf16(al[s][m], bh[s][n], acc[m][n], 0, 0, 0);
                    acc[m][n] = __builtin_amdgcn_mfma_f32_16x16x32_bf16(ah[s][m], bh[s][n], acc[m][n], 0, 0, 0);
                }
        float nas[4][4];
#pragma unroll
        for (int m = 0; m < 4; ++m) {
            float4 v = *(const float4*)&g_norms[bi * 128 + wr * 64 + m * 16 + (l >> 4) * 4];
            nas[m][0] = v.x * g0; nas[m][1] = v.y * g0;
            nas[m][2] = v.z * g0; nas[m][3] = v.w * g0;
        }
        float nbv[4];
#pragma unroll
        for (int n = 0; n < 4; ++n)
            nbv[n] = g_norms[bj * 128 + wc * 64 + n * 16 + (l & 15)] * g0;
        float part4[4] = {0.f, 0.f, 0.f, 0.f};
#pragma unroll
        for (int m = 0; m < 4; ++m)
#pragma unroll
            for (int n = 0; n < 4; ++n)
#pragma unroll
                for (int r = 0; r < 4; ++r)
                    part4[r] += fmaf(acc[m][n][r], c2, nas[m][r] + nbv[n]);
        float part = (part4[0] + part4[1]) + (part4[2] + part4[3]);
#pragma unroll
        for (int off = 32; off; off >>= 1) part += __shfl_down(part, off, 64);
        if (l == 0) sred[w] = part;
        __syncthreads();
        if (t == 0) g_dummy[id] = sred[0] + sred[1] + sred[2] + sred[3];
        __syncthreads();
    }
}

// Deterministic tree reduce of the 2080 per-pair doubles.
__global__ __launch_bounds__(256) void mmd_out(float* __restrict__ out) {
    __shared__ double wred[4];
    int t = threadIdx.x;
    double s = 0.0;
    for (int i = t; i < NPAIR; i += 256) s += g_part[i];
#pragma unroll
    for (int off = 32; off; off >>= 1) s += __shfl_down(s, off, 64);
    if ((t & 63) == 0) wred[t >> 6] = s;
    __syncthreads();
    if (t == 0)
        out[0] = (float)((wred[0] + wred[1] + wred[2] + wred[3]) * (1.0 / 16777216.0));
}

extern "C" void kernel_launch(void* const* d_in, const int* in_sizes, int n_in,
                              void* d_out, int out_size, void* d_ws, size_t ws_size,
                              hipStream_t stream) {
    const float* src = (const float*)d_in[0];
    const float* tgt = (const float*)d_in[1];
    float* out = (float*)d_out;

    mmd_prep<<<256, 256, 0, stream>>>(src, tgt);
    mmd_bw<<<1, 256, 0, stream>>>();
    mmd_main<<<MAIN_GRID, 256, 0, stream>>>();        // producer (same L2 state as R6)
    mmd_abl_loads<<<MAIN_GRID, 256, 0, stream>>>();   // diagnostics below
    mmd_abl_loadmfma<<<MAIN_GRID, 256, 0, stream>>>();
    mmd_abl_noexp<<<MAIN_GRID, 256, 0, stream>>>();
    mmd_out<<<1, 256, 0, stream>>>(out);
}

// Round 8
// 42.749 us; speedup vs baseline: 1.8342x; 1.8342x over previous
//
#include <hip/hip_runtime.h>
#include <math.h>

#define N_HALF 4096
#define D 64
#define M_TOT 8192
#define NPAIR 2080  // 64*65/2 upper-triangle 128x128 tile pairs

typedef short short8_t __attribute__((ext_vector_type(8)));
typedef unsigned short us8 __attribute__((ext_vector_type(8)));
typedef float f32x4 __attribute__((ext_vector_type(4)));

// Device-global scratch (fully rewritten by plain stores every call).
__device__ unsigned short Fhi[M_TOT * D];  // 1 MB fragment-major bf16 hi
__device__ unsigned short Flo[M_TOT * D];  // 1 MB bf16 lo residue
__device__ float g_norms[M_TOT];
__device__ float g_pssq[256];      // per-prep-block sum-of-squares partials
__device__ float g_pcol[256 * D];  // per-prep-block column-sum partials [b][c]
__device__ float g_coef;           // base exp2 coefficient g0
__device__ double g_part[NPAIR];   // per-pair signed partial sums

static __device__ inline unsigned short f2bf(float x) {
    union { float f; unsigned u; } v; v.f = x;
    unsigned r = v.u + 0x7fff + ((v.u >> 16) & 1);  // RNE
    return (unsigned short)(r >> 16);
}
static __device__ inline float bf2f(unsigned short h) {
    union { unsigned u; float f; } v; v.u = ((unsigned)h) << 16;
    return v.f;
}

// Fused: split-bf16 convert to fragment-major + row norms + block partials.
// F[rt][s][lane][e] = X[rt*16 + (lane&15)][s*32 + (lane>>4)*8 + e]
__global__ __launch_bounds__(256) void mmd_prep(const float* __restrict__ src,
                                                const float* __restrict__ tgt) {
    __shared__ float cs[D];
    __shared__ float hn[4][16];
    int t = threadIdx.x;
    if (t < D) cs[t] = 0.f;
    __syncthreads();
    int tid = blockIdx.x * 256 + t;  // 65536 threads total
    int l = tid & 63;
    int rs = tid >> 6;
    int s = rs & 1, rt = rs >> 1;
    int row = rt * 16 + (l & 15);
    int k0 = s * 32 + (l >> 4) * 8;
    const float* X = (row < N_HALF) ? src + (size_t)row * D
                                    : tgt + (size_t)(row - N_HALF) * D;
    float4 v0 = ((const float4*)(X + k0))[0];
    float4 v1 = ((const float4*)(X + k0))[1];
    float vs[8] = {v0.x, v0.y, v0.z, v0.w, v1.x, v1.y, v1.z, v1.w};
    us8 h, o;
    float p = 0.f;
#pragma unroll
    for (int e = 0; e < 8; ++e) {
        unsigned short hi = f2bf(vs[e]);
        h[e] = hi;
        o[e] = f2bf(vs[e] - bf2f(hi));
        p += vs[e] * vs[e];
    }
    ((us8*)Fhi)[tid] = h;
    ((us8*)Flo)[tid] = o;
#pragma unroll
    for (int e = 0; e < 8; ++e) atomicAdd(&cs[k0 + e], vs[e]);  // LDS only
    p += __shfl_down(p, 32, 64);
    p += __shfl_down(p, 16, 64);
    int w = t >> 6;
    if (l < 16) hn[w][l] = p;
    __syncthreads();
    if (t < 64) {
        float nr = 0.f;
        int tile = t >> 4, r = t & 15;
        if (t < 32) {
            nr = hn[tile * 2][r] + hn[tile * 2 + 1][r];
            g_norms[(blockIdx.x * 2 + tile) * 16 + r] = nr;
        }
        nr += __shfl_down(nr, 32, 64);
        nr += __shfl_down(nr, 16, 64);
        nr += __shfl_down(nr, 8, 64);
        nr += __shfl_down(nr, 4, 64);
        nr += __shfl_down(nr, 2, 64);
        nr += __shfl_down(nr, 1, 64);
        if (t == 0) g_pssq[blockIdx.x] = nr;
    }
    if (t < D) g_pcol[blockIdx.x * D + t] = cs[t];
}

// Bandwidth coefficient, one small block.
__global__ __launch_bounds__(256) void mmd_bw() {
    __shared__ float scol[4][64];
    __shared__ float sssq[4];
    int t = threadIdx.x, w = t >> 6, l = t & 63;
    float csum = 0.f;
#pragma unroll 16
    for (int q = 0; q < 64; ++q) csum += g_pcol[(w * 64 + q) * 64 + l];
    float sq = g_pssq[w * 64 + l];
#pragma unroll
    for (int off = 32; off; off >>= 1) sq += __shfl_xor(sq, off, 64);
    scol[w][l] = csum;
    if (l == 0) sssq[w] = sq;
    __syncthreads();
    if (t < 64) {
        float colsum = (scol[0][l] + scol[1][l]) + (scol[2][l] + scol[3][l]);
        float s2 = colsum * colsum;
#pragma unroll
        for (int off = 32; off; off >>= 1) s2 += __shfl_xor(s2, off, 64);
        if (t == 0) {
            float ssq = (sssq[0] + sssq[1]) + (sssq[2] + sssq[3]);
            const float M = (float)M_TOT;
            float sumL2 = 2.f * M * ssq - 2.f * s2;
            float bwq = sumL2 / (M * M - M) * 0.25f;
            g_coef = -1.4426950408889634f / (bwq * 16.f);
        }
    }
}

static __device__ inline void decode_pair(int id, int& bi, int& bj) {
    bi = (int)(64.5f - sqrtf(4160.25f - 2.0f * (float)id));
    while ((64 * (bi + 1) - ((bi + 1) * bi) / 2) <= id) ++bi;
    while ((64 * bi - (bi * (bi - 1)) / 2) > id) --bi;
    bj = bi + (id - (64 * bi - (bi * (bi - 1)) / 2));
}

// Main: one 128x128 pair tile per block, 8 waves of 64x32 each.
// Small accumulator (acc[4][2] = 32 AGPRs) + s-loop load-near-use keeps
// combined register use ~100 -> ~5 waves/SIMD resident to hide the
// exp2->squaring latency chains diagnosed in R7's ablation.
__global__ __launch_bounds__(512) void mmd_main() {
    __shared__ float sred[8];
    int t = threadIdx.x, w = t >> 6, l = t & 63;
    int wr = w >> 2, wc = w & 3;  // 2x4 wave grid: 64 rows x 32 cols per wave
    float g0 = g_coef;
    float c2 = -2.f * g0;
    const short8_t* FH = (const short8_t*)Fhi;
    const short8_t* FL = (const short8_t*)Flo;

    int bi, bj;
    decode_pair(blockIdx.x, bi, bj);

    f32x4 acc[4][2] = {};
#pragma unroll
    for (int s = 0; s < 2; ++s) {
        short8_t bh[2];
#pragma unroll
        for (int n = 0; n < 2; ++n)
            bh[n] = FH[((bj * 8 + wc * 2 + n) * 2 + s) * 64 + l];
#pragma unroll
        for (int m = 0; m < 4; ++m) {
            int fi = ((bi * 8 + wr * 4 + m) * 2 + s) * 64 + l;
            short8_t ah = FH[fi];
            short8_t al = FL[fi];
#pragma unroll
            for (int n = 0; n < 2; ++n) {
                acc[m][n] = __builtin_amdgcn_mfma_f32_16x16x32_bf16(al, bh[n], acc[m][n], 0, 0, 0);
                acc[m][n] = __builtin_amdgcn_mfma_f32_16x16x32_bf16(ah, bh[n], acc[m][n], 0, 0, 0);
            }
        }
    }

    // Epilogue: l2 -> 5 bandwidths via 1 exp2 + 4 squarings per output.
    float nas[4][4];
#pragma unroll
    for (int m = 0; m < 4; ++m) {
        float4 v = *(const float4*)&g_norms[bi * 128 + wr * 64 + m * 16 + (l >> 4) * 4];
        nas[m][0] = v.x * g0; nas[m][1] = v.y * g0;
        nas[m][2] = v.z * g0; nas[m][3] = v.w * g0;
    }
    float nbv[2];
#pragma unroll
    for (int n = 0; n < 2; ++n)
        nbv[n] = g_norms[bj * 128 + wc * 32 + n * 16 + (l & 15)] * g0;

    float part4[4] = {0.f, 0.f, 0.f, 0.f};
#pragma unroll
    for (int m = 0; m < 4; ++m)
#pragma unroll
        for (int n = 0; n < 2; ++n)
#pragma unroll
            for (int r = 0; r < 4; ++r) {
                float t0 = fmaf(acc[m][n][r], c2, nas[m][r] + nbv[n]);
                float k4 = __builtin_amdgcn_exp2f(t0);
                float k3 = k4 * k4;
                float k2 = k3 * k3;
                float k1 = k2 * k2;
                float k0 = k1 * k1;
                part4[r] += (k4 + k3) + ((k2 + k1) + k0);
            }
    float part = (part4[0] + part4[1]) + (part4[2] + part4[3]);

#pragma unroll
    for (int off = 32; off; off >>= 1) part += __shfl_down(part, off, 64);
    if (l == 0) sred[w] = part;
    __syncthreads();
    if (t == 0) {
        float tot = ((sred[0] + sred[1]) + (sred[2] + sred[3])) +
                    ((sred[4] + sred[5]) + (sred[6] + sred[7]));
        float sgn = ((bi < 32) == (bj < 32)) ? 1.f : -1.f;
        float scl = (bi == bj) ? 1.f : 2.f;
        g_part[blockIdx.x] = (double)tot * (double)(sgn * scl);
    }
}

// Deterministic tree reduce of the 2080 per-pair doubles.
__global__ __launch_bounds__(256) void mmd_out(float* __restrict__ out) {
    __shared__ double wred[4];
    int t = threadIdx.x;
    double s = 0.0;
    for (int i = t; i < NPAIR; i += 256) s += g_part[i];
#pragma unroll
    for (int off = 32; off; off >>= 1) s += __shfl_down(s, off, 64);
    if ((t & 63) == 0) wred[t >> 6] = s;
    __syncthreads();
    if (t == 0)
        out[0] = (float)((wred[0] + wred[1] + wred[2] + wred[3]) * (1.0 / 16777216.0));
}

extern "C" void kernel_launch(void* const* d_in, const int* in_sizes, int n_in,
                              void* d_out, int out_size, void* d_ws, size_t ws_size,
                              hipStream_t stream) {
    const float* src = (const float*)d_in[0];
    const float* tgt = (const float*)d_in[1];
    float* out = (float*)d_out;

    mmd_prep<<<256, 256, 0, stream>>>(src, tgt);
    mmd_bw<<<1, 256, 0, stream>>>();
    mmd_main<<<NPAIR, 512, 0, stream>>>();
    mmd_out<<<1, 256, 0, stream>>>(out);
}